// Round 5
// baseline (509.424 us; speedup 1.0000x reference)
//
#include <hip/hip_runtime.h>
#include <hip/hip_bf16.h>
#include <cstdint>
#include <cstddef>

#define SEQ 512
#define BATCH 256
#define IN_DIM 300
#define HID 256

typedef __attribute__((ext_vector_type(8))) short bf16x8;
typedef __attribute__((ext_vector_type(4))) float f32x4;

__device__ __forceinline__ float bitsf(unsigned int u) {
  union { unsigned int u; float f; } v; v.u = u; return v.f;
}
__device__ __forceinline__ unsigned int pk2(float a, float b) {
  union { __hip_bfloat162 h2; unsigned int u; } p;
  p.h2 = __float22bfloat162_rn(make_float2(a, b));
  return p.u;
}
__device__ __forceinline__ bf16x8 cvt8(float a0,float a1,float a2,float a3,
                                       float a4,float a5,float a6,float a7) {
  union { __hip_bfloat162 h2[4]; bf16x8 v; } c;
  c.h2[0] = __float22bfloat162_rn(make_float2(a0, a1));
  c.h2[1] = __float22bfloat162_rn(make_float2(a2, a3));
  c.h2[2] = __float22bfloat162_rn(make_float2(a4, a5));
  c.h2[3] = __float22bfloat162_rn(make_float2(a6, a7));
  return c.v;
}

// ---------------- kernel 1: xp2 (scan-permuted, bf16) = 2*(x@W_ih^T + b_ih + b_hh)
// Scan consumption layout: value (t, b, n) -> dword (t*64 + (b>>2))*512
//   + (n>>5)*64 + (b&3)*16 + (n&15); low short = col-half (n>>4)&1 == 0.
// W_ih staged f32 -> bf16 in-register (no pre-pass kernel). Staging loads
// software-pipelined one K-iter ahead.
__global__ __launch_bounds__(256) void gemm_xp(const float* __restrict__ x,
    const float* __restrict__ W_ih, const float* __restrict__ b_ih,
    const float* __restrict__ b_hh, unsigned int* __restrict__ xp2)
{
  __shared__ unsigned short a_lds[64][40];
  __shared__ unsigned short w_lds[256][40];
  const int tid  = threadIdx.x;
  const int wave = tid >> 6;
  const int lane = tid & 63;
  const int l15  = lane & 15;
  const int quad = lane >> 4;
  const long m0 = (long)blockIdx.x * 64;

  f32x4 acc[4][4];
  #pragma unroll
  for (int mt = 0; mt < 4; ++mt)
    #pragma unroll
    for (int nt = 0; nt < 4; ++nt) acc[mt][nt] = (f32x4){0.f, 0.f, 0.f, 0.f};

  const int ar = tid >> 2;
  const int ac = (tid & 3) * 8;

  float av[8];
  float4 wv[8];
  // prefetch kc=0
  {
    const float* src = x + (size_t)(m0 + ar) * IN_DIM + ac;
    float2 p0 = *(const float2*)(src + 0);
    float2 p1 = *(const float2*)(src + 2);
    float2 p2 = *(const float2*)(src + 4);
    float2 p3 = *(const float2*)(src + 6);
    av[0]=p0.x; av[1]=p0.y; av[2]=p1.x; av[3]=p1.y;
    av[4]=p2.x; av[5]=p2.y; av[6]=p3.x; av[7]=p3.y;
    #pragma unroll
    for (int i = 0; i < 8; ++i) {
      int e = tid + i * 256;
      wv[i] = *(const float4*)(W_ih + (e >> 3) * IN_DIM + (e & 7) * 4);
    }
  }

  for (int kc = 0; kc < 10; ++kc) {
    *(bf16x8*)&a_lds[ar][ac] = cvt8(av[0],av[1],av[2],av[3],av[4],av[5],av[6],av[7]);
    #pragma unroll
    for (int i = 0; i < 8; ++i) {
      int e = tid + i * 256;
      union { unsigned int u[2]; uint2 d; } pk;
      pk.u[0] = pk2(wv[i].x, wv[i].y);
      pk.u[1] = pk2(wv[i].z, wv[i].w);
      *(uint2*)&w_lds[e >> 3][(e & 7) * 4] = pk.d;
    }
    __syncthreads();
    // prefetch kc+1 (overlaps frag reads + MFMA)
    if (kc < 9) {
      const int k0 = (kc + 1) * 32;
      const float* src = x + (size_t)(m0 + ar) * IN_DIM + (k0 + ac);
      if (k0 + ac + 8 <= IN_DIM) {
        float2 p0 = *(const float2*)(src + 0);
        float2 p1 = *(const float2*)(src + 2);
        float2 p2 = *(const float2*)(src + 4);
        float2 p3 = *(const float2*)(src + 6);
        av[0]=p0.x; av[1]=p0.y; av[2]=p1.x; av[3]=p1.y;
        av[4]=p2.x; av[5]=p2.y; av[6]=p3.x; av[7]=p3.y;
      } else {
        #pragma unroll
        for (int j = 0; j < 8; ++j) av[j] = (k0 + ac + j < IN_DIM) ? src[j] : 0.f;
      }
      #pragma unroll
      for (int i = 0; i < 8; ++i) {
        int e = tid + i * 256;
        int kk = k0 + (e & 7) * 4;
        wv[i] = (kk + 4 <= IN_DIM)
              ? *(const float4*)(W_ih + (e >> 3) * IN_DIM + kk)
              : make_float4(0.f, 0.f, 0.f, 0.f);
      }
    }
    bf16x8 afr[4], bfr[4];
    #pragma unroll
    for (int mt = 0; mt < 4; ++mt)
      afr[mt] = *(const bf16x8*)&a_lds[mt*16 + l15][quad*8];
    #pragma unroll
    for (int nt = 0; nt < 4; ++nt)
      bfr[nt] = *(const bf16x8*)&w_lds[wave*64 + nt*16 + l15][quad*8];
    #pragma unroll
    for (int mt = 0; mt < 4; ++mt)
      #pragma unroll
      for (int nt = 0; nt < 4; ++nt)
        acc[mt][nt] = __builtin_amdgcn_mfma_f32_16x16x32_bf16(afr[mt], bfr[nt], acc[mt][nt], 0, 0, 0);
    __syncthreads();
  }
  // epilogue: pack col-halves (nt even/odd) into dwords, scatter to scan layout
  const int t = (int)(blockIdx.x >> 2);
  const float kb0 = 2.0f * (b_ih[wave*64 +  0 + l15] + b_hh[wave*64 +  0 + l15]);
  const float kb1 = 2.0f * (b_ih[wave*64 + 16 + l15] + b_hh[wave*64 + 16 + l15]);
  const float kb2 = 2.0f * (b_ih[wave*64 + 32 + l15] + b_hh[wave*64 + 32 + l15]);
  const float kb3 = 2.0f * (b_ih[wave*64 + 48 + l15] + b_hh[wave*64 + 48 + l15]);
  #pragma unroll
  for (int mt = 0; mt < 4; ++mt) {
    const int g = ((int)(blockIdx.x & 3))*16 + mt*4 + quad;
    const size_t base = ((size_t)t*64 + g)*512;
    #pragma unroll
    for (int r = 0; r < 4; ++r) {
      unsigned int d0 = pk2(fmaf(2.0f, acc[mt][0][r], kb0), fmaf(2.0f, acc[mt][1][r], kb1));
      unsigned int d1 = pk2(fmaf(2.0f, acc[mt][2][r], kb2), fmaf(2.0f, acc[mt][3][r], kb3));
      xp2[base + (wave*2    )*64 + r*16 + l15] = d0;
      xp2[base + (wave*2 + 1)*64 + r*16 + l15] = d1;
    }
  }
}

// ---------------- kernel 2: sequential scan. 64 blocks x 512 thr (8 waves).
// Block g owns batches [4g, 4g+4). Wave w owns hidden cols [32w, 32w+32).
// k-PERMUTED LDS layout: position p (within 32-chunk cc) <-> logical col
// k = cc*32 + (p&31)>>1 + 16*(p&1). Applied identically to A-positions and
// W B-frags, so MFMA sums are unchanged. Payoff: each lane's two h outputs
// (cols c, c+16, same batch) are LDS-adjacent -> ONE ds_write_b32.
// Quad accumulator chains cut MFMA dependency depth 4 -> 2.
// xp read in 32-step register bursts (one vmcnt drain per 32 barriers).
__global__ __launch_bounds__(512) void rnn_scan(const float* __restrict__ W_hh,
    const unsigned int* __restrict__ xp2, float* __restrict__ hT)
{
  __shared__ alignas(16) unsigned short hbuf[2][4 * 272];
  const int tid  = threadIdx.x;
  const int wave = tid >> 6;
  const int lane = tid & 63;
  const int l15  = lane & 15;
  const int quad = lane >> 4;
  const int g = blockIdx.x;
  const int c0 = wave * 32;

  // B fragments with permuted k: wf[nt][kc][j] = W_hh[n][kc*32 + quad*4 + (j>>1) + 16*(j&1)]
  bf16x8 wf[2][8];
  #pragma unroll
  for (int nt = 0; nt < 2; ++nt) {
    const int n = c0 + nt*16 + l15;
    #pragma unroll
    for (int kc = 0; kc < 8; ++kc) {
      const float* src = W_hh + n*HID + kc*32 + quad*4;
      float4 p0 = *(const float4*)src;          // k = base+0..3
      float4 p1 = *(const float4*)(src + 16);   // k = base+16..19
      wf[nt][kc] = cvt8(p0.x,p1.x,p0.y,p1.y,p0.z,p1.z,p0.w,p1.w);
    }
  }

  const int abase = (l15 & 3) * 272 + quad * 8;          // A-frag read base (shorts)
  const int wofs  = quad * 272 + wave * 32 + l15 * 2;    // h write offset (shorts)

  for (int i = tid; i < 4 * 272; i += 512) hbuf[0][i] = 0;  // h0 = 0

  const unsigned int* xbase = xp2 + (size_t)g * 512 + tid;  // t stride 32768 dwords

  __syncthreads();

  unsigned int xq[32];
  for (int tc = 0; tc < SEQ / 32; ++tc) {
    const unsigned int* pb = xbase + (size_t)tc * 32 * 32768;
    #pragma unroll
    for (int j = 0; j < 32; ++j)
      xq[j] = pb[(size_t)j * 32768];
    #pragma unroll
    for (int j = 0; j < 32; ++j) {
      const int cur = j & 1;                     // t parity == j parity
      bf16x8 afr[8];
      #pragma unroll
      for (int kc = 0; kc < 8; ++kc)
        afr[kc] = *(const bf16x8*)&hbuf[cur][abase + kc*32];
      f32x4 c00 = (f32x4){0.f,0.f,0.f,0.f}, c01 = c00, c10 = c00, c11 = c00;
      #pragma unroll
      for (int kc = 0; kc < 8; kc += 2) {
        c00 = __builtin_amdgcn_mfma_f32_16x16x32_bf16(afr[kc],   wf[0][kc],   c00, 0, 0, 0);
        c10 = __builtin_amdgcn_mfma_f32_16x16x32_bf16(afr[kc],   wf[1][kc],   c10, 0, 0, 0);
        c01 = __builtin_amdgcn_mfma_f32_16x16x32_bf16(afr[kc+1], wf[0][kc+1], c01, 0, 0, 0);
        c11 = __builtin_amdgcn_mfma_f32_16x16x32_bf16(afr[kc+1], wf[1][kc+1], c11, 0, 0, 0);
      }
      // lane keeps batch q=quad only: D row quad*4+r holds batch r, so
      // reg index = quad selects this lane's batch.
      const bool qb0 = (quad & 1) != 0, qb1 = (quad & 2) != 0;
      float a0 = qb1 ? (qb0 ? c00[3]+c01[3] : c00[2]+c01[2])
                     : (qb0 ? c00[1]+c01[1] : c00[0]+c01[0]);
      float a1 = qb1 ? (qb0 ? c10[3]+c11[3] : c10[2]+c11[2])
                     : (qb0 ? c10[1]+c11[1] : c10[0]+c11[0]);
      float xv0 = bitsf(xq[j] << 16);
      float xv1 = bitsf(xq[j] & 0xffff0000u);
      float y0 = fmaf(2.0f, a0, xv0);            // 2*(h@W^T + x + b)
      float y1 = fmaf(2.0f, a1, xv1);
      float h0 = fmaf(-2.0f, __builtin_amdgcn_rcpf(__expf(y0) + 1.0f), 1.0f);
      float h1 = fmaf(-2.0f, __builtin_amdgcn_rcpf(__expf(y1) + 1.0f), 1.0f);
      if (j < 31 || tc < SEQ/32 - 1) {
        *(unsigned int*)&hbuf[1 - cur][wofs] = pk2(h0, h1);  // cols c0+l15, c0+16+l15
      } else {
        hT[(size_t)(g*4 + quad) * HID + c0 + l15]      = h0;
        hT[(size_t)(g*4 + quad) * HID + c0 + 16 + l15] = h1;
      }
      __syncthreads();
    }
  }
}

// ---------------- kernel 3: logits + log_softmax. 1 wave/batch.
__global__ __launch_bounds__(64) void fc_head(const float* __restrict__ hT,
    const float* __restrict__ W_fc, const float* __restrict__ b_fc,
    float* __restrict__ out)
{
  const int b = blockIdx.x;
  const int l = threadIdx.x;
  float s0 = 0.f, s1 = 0.f;
  #pragma unroll
  for (int j0 = 0; j0 < HID; j0 += 64) {
    float h = hT[(size_t)b * HID + j0 + l];
    s0 += h * W_fc[j0 + l];
    s1 += h * W_fc[HID + j0 + l];
  }
  #pragma unroll
  for (int off = 32; off > 0; off >>= 1) {
    s0 += __shfl_xor(s0, off, 64);
    s1 += __shfl_xor(s1, off, 64);
  }
  if (l == 0) {
    float l0 = s0 + b_fc[0], l1 = s1 + b_fc[1];
    float m = fmaxf(l0, l1);
    float lse = m + logf(expf(l0 - m) + expf(l1 - m));
    out[b*2 + 0] = l0 - lse;
    out[b*2 + 1] = l1 - lse;
  }
}

extern "C" void kernel_launch(void* const* d_in, const int* in_sizes, int n_in,
                              void* d_out, int out_size, void* d_ws, size_t ws_size,
                              hipStream_t stream) {
  const float* x    = (const float*)d_in[0];
  const float* W_ih = (const float*)d_in[1];
  const float* W_hh = (const float*)d_in[2];
  const float* b_ih = (const float*)d_in[3];
  const float* b_hh = (const float*)d_in[4];
  const float* W_fc = (const float*)d_in[5];
  const float* b_fc = (const float*)d_in[6];
  float* out = (float*)d_out;

  const size_t xp_bytes = (size_t)SEQ * BATCH * HID * 2;   // 67,108,864
  const size_t ht_bytes = (size_t)BATCH * HID * 4;
  if (ws_size < xp_bytes + ht_bytes) return;

  char* ws = (char*)d_ws;
  unsigned int* xp2 = (unsigned int*)ws;
  float*        hT  = (float*)(ws + xp_bytes);

  hipLaunchKernelGGL(gemm_xp,  dim3(2048), dim3(256), 0, stream, x, W_ih, b_ih, b_hh, xp2);
  hipLaunchKernelGGL(rnn_scan, dim3(64),   dim3(512), 0, stream, W_hh, xp2, hT);
  hipLaunchKernelGGL(fc_head,  dim3(BATCH), dim3(64), 0, stream, hT, W_fc, b_fc, out);
}